// Round 16
// baseline (113.072 us; speedup 1.0000x reference)
//
#include <hip/hip_runtime.h>

#define NB_B  2
#define NB_Q  10000
#define NB_D  256
#define NB_NH 8
#define NB_NL 4
#define NB_NP 4
#define NB_HD 32
#define NB_S  21760   // 128*128 + 64*64 + 32*32 + 16*16
#define MQ    20000   // B*Q
#define GSTR  32768   // tiled-weight group stride in halfs: 8kt*4oct*128n*8

#define NVF   5440    // vproj wave-slices:  (43520/32) * 4 ngroups
#define NCF   3750    // coords wave-slices: (20000/32) * 6 ngroups
#define NSF   (NVF + NCF)          // 9190
#define NFB   ((NSF + 3) / 4)      // 2298 front blocks (256 thr = 4 waves)
#define NOS   2500    // oproj wave-slices: (20000/32) * 4 ngroups
#define NOB   (NOS / 4)            // 625

typedef _Float16 half8 __attribute__((ext_vector_type(8)));
typedef float f32x4 __attribute__((ext_vector_type(4)));

// ---------------------------------------------------------------------------
// Prep: transpose + fp16-convert weights into per-K-step tiled layout:
//   W_tiled[g][kt][oct][nl][8]   (g = n>>7, nl = n&127, k = kt*32+oct*8+off)
// ---------------------------------------------------------------------------
__device__ __forceinline__ size_t wtile_idx(int n, int k) {
    return (size_t)(n >> 7) * GSTR + (k >> 5) * 4096 + ((k >> 3) & 3) * 1024
         + (n & 127) * 8 + (k & 7);
}

__global__ __launch_bounds__(256) void k_prepw(const float* __restrict__ Wv,
                                               const float* __restrict__ Ws,
                                               const float* __restrict__ Wa,
                                               const float* __restrict__ Wo,
                                               _Float16* __restrict__ Wvt,
                                               _Float16* __restrict__ Wsat,
                                               _Float16* __restrict__ Wot)
{
    const int k = threadIdx.x;
    const int nc = blockIdx.x;
    if (nc < 256) {
        Wvt[wtile_idx(nc, k)] = (_Float16)Wv[k * 256 + nc];
    } else if (nc < 640) {
        const int n = nc - 256;
        const float v = (n < 256) ? Ws[k * 256 + n] : Wa[k * 128 + (n - 256)];
        Wsat[wtile_idx(n, k)] = (_Float16)v;
    } else {
        const int n = nc - 640;
        Wot[wtile_idx(n, k)] = (_Float16)Wo[k * 256 + n];
    }
}

// ---------------------------------------------------------------------------
// k_front: 4 INDEPENDENT waves per block, each owns a 32x64 output tile.
// No LDS, no barriers. Per K-step: A 4x float4 (coalesced 128B/row segs,
// L3-backed) -> cvt fp16; B 4x half8 from PRE-TILED weights (256B-contig,
// L2-hot); 8 MFMA. Compiler free to pipeline across steps.
//   slices [0,NVF): vproj (ng=slice&3, rows (slice>>2)*32)
//   slices [NVF,NSF): coords (ng=cs%6: 0-3 offsets, 4-5 logits)
// ---------------------------------------------------------------------------
__global__ __launch_bounds__(256) void k_front(const float* __restrict__ value,
                                               const float* __restrict__ query,
                                               const _Float16* __restrict__ Wvt,
                                               const _Float16* __restrict__ Wsat,
                                               const float* __restrict__ refp,
                                               const float* __restrict__ bv,
                                               const float* __restrict__ bs,
                                               const float* __restrict__ ba,
                                               _Float16* __restrict__ vt,
                                               float* __restrict__ sx,
                                               float* __restrict__ sy,
                                               float* __restrict__ sw)
{
    const int slice = blockIdx.x * 4 + (threadIdx.x >> 6);
    if (slice >= NSF) return;
    const int lane = threadIdx.x & 63;
    const int rowb = lane & 15, kq = lane >> 4;

    bool isv;
    int row0, ng;
    const float* Asrc;
    const _Float16* Wt;
    if (slice < NVF) {
        isv = true;
        ng = slice & 3;
        row0 = (slice >> 2) * 32;
        Asrc = value;
        Wt = Wvt;
    } else {
        isv = false;
        const int cs = slice - NVF;
        ng = cs % 6;
        row0 = (cs / 6) * 32;
        Asrc = query;
        Wt = Wsat;
    }
    const int n0 = ng * 64;

    // B fragment base (pre-tiled): + kt*4096 + fc*128 per access
    const _Float16* Bt = Wt + (size_t)(n0 >> 7) * GSTR + kq * 1024
                       + ((n0 & 127) + rowb) * 8;
    // A fragment rows (32B contiguous per lane; 4 kq-lanes per row -> 128B segs)
    const float* gA0 = Asrc + (size_t)(row0 + rowb) * 256 + kq * 8;
    const float* gA1 = Asrc + (size_t)(row0 + 16 + rowb) * 256 + kq * 8;

    f32x4 acc[2][4];
#pragma unroll
    for (int fr = 0; fr < 2; ++fr)
#pragma unroll
        for (int fc = 0; fc < 4; ++fc) acc[fr][fc] = (f32x4){0.f, 0.f, 0.f, 0.f};

#pragma unroll
    for (int kt = 0; kt < 8; ++kt) {
        const float4 x00 = *reinterpret_cast<const float4*>(gA0 + kt * 32);
        const float4 x01 = *reinterpret_cast<const float4*>(gA0 + kt * 32 + 4);
        const float4 x10 = *reinterpret_cast<const float4*>(gA1 + kt * 32);
        const float4 x11 = *reinterpret_cast<const float4*>(gA1 + kt * 32 + 4);
        half8 bf[4];
#pragma unroll
        for (int fc = 0; fc < 4; ++fc)
            bf[fc] = *reinterpret_cast<const half8*>(Bt + kt * 4096 + fc * 128);
        half8 af0, af1;
        af0[0] = (_Float16)x00.x; af0[1] = (_Float16)x00.y;
        af0[2] = (_Float16)x00.z; af0[3] = (_Float16)x00.w;
        af0[4] = (_Float16)x01.x; af0[5] = (_Float16)x01.y;
        af0[6] = (_Float16)x01.z; af0[7] = (_Float16)x01.w;
        af1[0] = (_Float16)x10.x; af1[1] = (_Float16)x10.y;
        af1[2] = (_Float16)x10.z; af1[3] = (_Float16)x10.w;
        af1[4] = (_Float16)x11.x; af1[5] = (_Float16)x11.y;
        af1[6] = (_Float16)x11.z; af1[7] = (_Float16)x11.w;
#pragma unroll
        for (int fc = 0; fc < 4; ++fc) {
            acc[0][fc] = __builtin_amdgcn_mfma_f32_16x16x32_f16(af0, bf[fc], acc[0][fc], 0, 0, 0);
            acc[1][fc] = __builtin_amdgcn_mfma_f32_16x16x32_f16(af1, bf[fc], acc[1][fc], 0, 0, 0);
        }
    }

    // ---- epilogues (per-wave; m = fr*16 + kq*4 + j, rows row0+m) ----
    if (isv) {
        const int b = (row0 >= NB_S) ? 1 : 0;
        const int sb = row0 - b * NB_S;
#pragma unroll
        for (int fc = 0; fc < 4; ++fc) {
            const int n = n0 + fc * 16 + rowb;
            const int h = n >> 5, hd = n & 31;
            const float bvn = bv[n];
#pragma unroll
            for (int fr = 0; fr < 2; ++fr) {
                const f32x4 c = acc[fr][fc];
#pragma unroll
                for (int j = 0; j < 4; ++j) {
                    const int m = fr * 16 + kq * 4 + j;
                    vt[((size_t)((b * NB_NH + h) * NB_S + (sb + m)) << 5) + hd] = (_Float16)(c[j] + bvn);
                }
            }
        }
    } else if (n0 < 256) {
#pragma unroll
        for (int fc = 0; fc < 4; ++fc) {
            const int n = n0 + fc * 16 + rowb;
            const int si = n >> 1, xy = n & 1;
            const int l = (n >> 3) & 3;
            const float dim = (float)(128 >> l);
            const float bsv = bs[n];
            float* dst = xy ? sy : sx;
#pragma unroll
            for (int fr = 0; fr < 2; ++fr) {
                const f32x4 c = acc[fr][fc];
#pragma unroll
                for (int j = 0; j < 4; ++j) {
                    const int m = fr * 16 + kq * 4 + j;
                    const float ref = refp[(size_t)(row0 + m) * 8 + l * 2 + xy];
                    const float coord = ref * dim + (c[j] + bsv) - 0.5f;
                    dst[(size_t)(row0 + m) * 128 + si] = coord;
                }
            }
        }
    } else {
#pragma unroll
        for (int fc = 0; fc < 4; ++fc) {
            const int col = n0 - 256 + fc * 16 + rowb;
            const float bav = ba[col];
#pragma unroll
            for (int fr = 0; fr < 2; ++fr) {
                const f32x4 c = acc[fr][fc];
#pragma unroll
                for (int j = 0; j < 4; ++j) {
                    const int m = fr * 16 + kq * 4 + j;
                    float v = c[j] + bav;
                    float vm = v;
                    vm = fmaxf(vm, __shfl_xor(vm, 1));
                    vm = fmaxf(vm, __shfl_xor(vm, 2));
                    vm = fmaxf(vm, __shfl_xor(vm, 4));
                    vm = fmaxf(vm, __shfl_xor(vm, 8));
                    const float e = expf(v - vm);
                    float s = e;
                    s += __shfl_xor(s, 1);
                    s += __shfl_xor(s, 2);
                    s += __shfl_xor(s, 4);
                    s += __shfl_xor(s, 8);
                    sw[(size_t)(row0 + m) * 128 + col] = e / s;
                }
            }
        }
    }
}

// ---------------------------------------------------------------------------
// gather: block = (16 queries, 1 head); head = blockIdx.x & 7 (XCD locality).
// ---------------------------------------------------------------------------
__global__ __launch_bounds__(256) void k_gather(const _Float16* __restrict__ vt,
                                                const float* __restrict__ sx,
                                                const float* __restrict__ sy,
                                                const float* __restrict__ sw,
                                                _Float16* __restrict__ tmp)
{
    __shared__ int   offs[16][16][4];
    __shared__ float wts[16][16][4];
    const int t = threadIdx.x;
    const int gid = blockIdx.x;
    const int h = gid & 7;
    const int row0 = (gid >> 3) * 16;
    const int b = (row0 >= NB_Q) ? 1 : 0;

    {
        const int r = t >> 4, s = t & 15;
        const size_t ci = (size_t)(row0 + r) * 128 + h * 16 + s;
        const float x = sx[ci], y = sy[ci], w = sw[ci];
        const int l = s >> 2;
        const int dim = 128 >> l;
        const int startL = (l == 0) ? 0 : (l == 1) ? 16384 : (l == 2) ? 20480 : 21504;
        const float x0f = floorf(x), y0f = floorf(y);
        const float lx = x - x0f, ly = y - y0f;
        const int ix = (int)x0f, iy = (int)y0f;
        const int ix0 = min(max(ix, 0), dim - 1), ix1 = min(max(ix + 1, 0), dim - 1);
        const int iy0 = min(max(iy, 0), dim - 1), iy1 = min(max(iy + 1, 0), dim - 1);
        const float vx0 = (ix >= 0 && ix < dim) ? 1.f : 0.f;
        const float vx1 = (ix + 1 >= 0 && ix + 1 < dim) ? 1.f : 0.f;
        const float vy0 = (iy >= 0 && iy < dim) ? 1.f : 0.f;
        const float vy1 = (iy + 1 >= 0 && iy + 1 < dim) ? 1.f : 0.f;
        offs[r][s][0] = (startL + iy0 * dim + ix0) * (NB_HD * 2);
        offs[r][s][1] = (startL + iy0 * dim + ix1) * (NB_HD * 2);
        offs[r][s][2] = (startL + iy1 * dim + ix0) * (NB_HD * 2);
        offs[r][s][3] = (startL + iy1 * dim + ix1) * (NB_HD * 2);
        wts[r][s][0] = w * (1.f - lx) * (1.f - ly) * vx0 * vy0;
        wts[r][s][1] = w * lx * (1.f - ly) * vx1 * vy0;
        wts[r][s][2] = w * (1.f - lx) * ly * vx0 * vy1;
        wts[r][s][3] = w * lx * ly * vx1 * vy1;
    }
    __syncthreads();

    const int r = t >> 4, hd2 = t & 15;
    const char* slab = reinterpret_cast<const char*>(vt)
                     + (size_t)(b * NB_NH + h) * NB_S * (NB_HD * 2);
    const int byo = hd2 * 4;
    float ax = 0.f, ay = 0.f;
#pragma unroll
    for (int s = 0; s < 16; ++s) {
        const int4   o = *reinterpret_cast<const int4*>(&offs[r][s][0]);
        const float4 w = *reinterpret_cast<const float4*>(&wts[r][s][0]);
        union { unsigned u; _Float16 h[2]; } c0, c1, c2, c3;
        c0.u = *reinterpret_cast<const unsigned*>(slab + (o.x + byo));
        c1.u = *reinterpret_cast<const unsigned*>(slab + (o.y + byo));
        c2.u = *reinterpret_cast<const unsigned*>(slab + (o.z + byo));
        c3.u = *reinterpret_cast<const unsigned*>(slab + (o.w + byo));
        ax = fmaf(w.x, (float)c0.h[0], ax); ay = fmaf(w.x, (float)c0.h[1], ay);
        ax = fmaf(w.y, (float)c1.h[0], ax); ay = fmaf(w.y, (float)c1.h[1], ay);
        ax = fmaf(w.z, (float)c2.h[0], ax); ay = fmaf(w.z, (float)c2.h[1], ay);
        ax = fmaf(w.w, (float)c3.h[0], ax); ay = fmaf(w.w, (float)c3.h[1], ay);
    }
    union { unsigned u; _Float16 h[2]; } p;
    p.h[0] = (_Float16)ax; p.h[1] = (_Float16)ay;
    *reinterpret_cast<unsigned*>(tmp + (size_t)(row0 + r) * 256 + h * 32 + hd2 * 2) = p.u;
}

// ---------------------------------------------------------------------------
// oproj: out = tmp @ Wo + bo. Wave-independent 32x64 tiles, no LDS/barriers.
// A fp16 direct (uint4/fr), B pre-tiled.
// ---------------------------------------------------------------------------
__global__ __launch_bounds__(256) void k_oproj_mm(const _Float16* __restrict__ tmp,
                                                  const _Float16* __restrict__ Wot,
                                                  const float* __restrict__ bo,
                                                  float* __restrict__ out)
{
    const int slice = blockIdx.x * 4 + (threadIdx.x >> 6);
    const int lane = threadIdx.x & 63;
    const int rowb = lane & 15, kq = lane >> 4;
    const int ng = slice & 3;
    const int row0 = (slice >> 2) * 32;
    const int n0 = ng * 64;

    const _Float16* Bt = Wot + (size_t)(n0 >> 7) * GSTR + kq * 1024
                       + ((n0 & 127) + rowb) * 8;
    const _Float16* gA0 = tmp + (size_t)(row0 + rowb) * 256 + kq * 8;
    const _Float16* gA1 = tmp + (size_t)(row0 + 16 + rowb) * 256 + kq * 8;

    f32x4 acc[2][4];
#pragma unroll
    for (int fr = 0; fr < 2; ++fr)
#pragma unroll
        for (int fc = 0; fc < 4; ++fc) acc[fr][fc] = (f32x4){0.f, 0.f, 0.f, 0.f};

#pragma unroll
    for (int kt = 0; kt < 8; ++kt) {
        const half8 af0 = *reinterpret_cast<const half8*>(gA0 + kt * 32);
        const half8 af1 = *reinterpret_cast<const half8*>(gA1 + kt * 32);
        half8 bf[4];
#pragma unroll
        for (int fc = 0; fc < 4; ++fc)
            bf[fc] = *reinterpret_cast<const half8*>(Bt + kt * 4096 + fc * 128);
#pragma unroll
        for (int fc = 0; fc < 4; ++fc) {
            acc[0][fc] = __builtin_amdgcn_mfma_f32_16x16x32_f16(af0, bf[fc], acc[0][fc], 0, 0, 0);
            acc[1][fc] = __builtin_amdgcn_mfma_f32_16x16x32_f16(af1, bf[fc], acc[1][fc], 0, 0, 0);
        }
    }

#pragma unroll
    for (int fc = 0; fc < 4; ++fc) {
        const int n = n0 + fc * 16 + rowb;
        const float bon = bo[n];
#pragma unroll
        for (int fr = 0; fr < 2; ++fr) {
            const f32x4 c = acc[fr][fc];
#pragma unroll
            for (int j = 0; j < 4; ++j) {
                const int m = fr * 16 + kq * 4 + j;
                out[(size_t)(row0 + m) * 256 + n] = c[j] + bon;
            }
        }
    }
}

// ---------------------------------------------------------------------------
extern "C" void kernel_launch(void* const* d_in, const int* in_sizes, int n_in,
                              void* d_out, int out_size, void* d_ws, size_t ws_size,
                              hipStream_t stream)
{
    const float* query = (const float*)d_in[0];
    const float* refp  = (const float*)d_in[1];
    const float* value = (const float*)d_in[2];
    const float* Wv = (const float*)d_in[4];
    const float* bv = (const float*)d_in[5];
    const float* Ws = (const float*)d_in[6];
    const float* bs = (const float*)d_in[7];
    const float* Wa = (const float*)d_in[8];
    const float* ba = (const float*)d_in[9];
    const float* Wo = (const float*)d_in[10];
    const float* bo = (const float*)d_in[11];
    float* out = (float*)d_out;

    char* ws = (char*)d_ws;
    _Float16* vt_h  = (_Float16*)(ws + 0);          // 43520*256*2   = 22,282,240 B
    _Float16* tmp_h = (_Float16*)(ws + 22282240);   // 20000*256*2   = 10,240,000 B
    _Float16* Wvt   = (_Float16*)(ws + 32522240);   //                   131,072 B
    _Float16* Wsat  = (_Float16*)(ws + 32653312);   //                   196,608 B
    _Float16* Wot   = (_Float16*)(ws + 32849920);   //                   131,072 B
    float*    sxg   = (float*)   (ws + 32980992);   // 20000*128*4   = 10,240,000 B
    float*    syg   = (float*)   (ws + 43220992);
    float*    swg   = (float*)   (ws + 53460992);   // ends 63,700,992

    hipLaunchKernelGGL(k_prepw, dim3(896), dim3(256), 0, stream,
                       Wv, Ws, Wa, Wo, Wvt, Wsat, Wot);
    hipLaunchKernelGGL(k_front, dim3(NFB), dim3(256), 0, stream,
                       value, query, Wvt, Wsat, refp, bv, bs, ba,
                       vt_h, sxg, syg, swg);
    hipLaunchKernelGGL(k_gather, dim3(NB_B * NB_Q / 16 * NB_NH), dim3(256), 0, stream,
                       vt_h, sxg, syg, swg, tmp_h);
    hipLaunchKernelGGL(k_oproj_mm, dim3(NOB), dim3(256), 0, stream,
                       tmp_h, Wot, bo, out);
}

// Round 17
// 103.447 us; speedup vs baseline: 1.0930x; 1.0930x over previous
//
#include <hip/hip_runtime.h>

#define NB_B  2
#define NB_Q  10000
#define NB_D  256
#define NB_NH 8
#define NB_NL 4
#define NB_NP 4
#define NB_HD 32
#define NB_S  21760   // 128*128 + 64*64 + 32*32 + 16*16
#define MQ    20000   // B*Q
#define MQB   313     // ceil(20000/64)
#define NVB   1360    // (B*S/64)*2  vproj blocks
#define NCB   939     // MQB*3       coords blocks

#define ASTR  536     // A oct stride in halfs
#define GSTR  32768   // tiled-weight group stride in halfs: 8kt*4oct*128n*8

typedef _Float16 half8 __attribute__((ext_vector_type(8)));
typedef float f32x4 __attribute__((ext_vector_type(4)));

// ---------------------------------------------------------------------------
// Prep + convert: blocks [0,896): weights -> fp16 per-K-step tiled layout;
// blocks [896,6336): value -> fp16; blocks [6336,8836): query -> fp16.
// ---------------------------------------------------------------------------
__device__ __forceinline__ size_t wtile_idx(int n, int k) {
    return (size_t)(n >> 7) * GSTR + (k >> 5) * 4096 + ((k >> 3) & 3) * 1024
         + (n & 127) * 8 + (k & 7);
}

__device__ __forceinline__ void cvt8(const float* src, _Float16* dst) {
    const float4 a = *reinterpret_cast<const float4*>(src);
    const float4 b = *reinterpret_cast<const float4*>(src + 4);
    half8 h;
    h[0] = (_Float16)a.x; h[1] = (_Float16)a.y; h[2] = (_Float16)a.z; h[3] = (_Float16)a.w;
    h[4] = (_Float16)b.x; h[5] = (_Float16)b.y; h[6] = (_Float16)b.z; h[7] = (_Float16)b.w;
    *reinterpret_cast<half8*>(dst) = h;
}

__global__ __launch_bounds__(256) void k_prepcvt(const float* __restrict__ Wv,
                                                 const float* __restrict__ Ws,
                                                 const float* __restrict__ Wa,
                                                 const float* __restrict__ Wo,
                                                 const float* __restrict__ value,
                                                 const float* __restrict__ query,
                                                 _Float16* __restrict__ Wvt,
                                                 _Float16* __restrict__ Wsat,
                                                 _Float16* __restrict__ Wot,
                                                 _Float16* __restrict__ val_h,
                                                 _Float16* __restrict__ qry_h)
{
    const int t = threadIdx.x;
    const int bid = blockIdx.x;
    if (bid < 896) {
        const int k = t;
        const int nc = bid;
        if (nc < 256) {
            Wvt[wtile_idx(nc, k)] = (_Float16)Wv[k * 256 + nc];
        } else if (nc < 640) {
            const int n = nc - 256;
            const float v = (n < 256) ? Ws[k * 256 + n] : Wa[k * 128 + (n - 256)];
            Wsat[wtile_idx(n, k)] = (_Float16)v;
        } else {
            const int n = nc - 640;
            Wot[wtile_idx(n, k)] = (_Float16)Wo[k * 256 + n];
        }
    } else if (bid < 6336) {
        const size_t i = ((size_t)(bid - 896) * 256 + t) * 8;   // < 11,141,120
        cvt8(value + i, val_h + i);
    } else {
        const size_t i = ((size_t)(bid - 6336) * 256 + t) * 8;  // < 5,120,000
        cvt8(query + i, qry_h + i);
    }
}

// ---------------------------------------------------------------------------
// k_front: co-launched vproj [0,NVB) + coords [NVB,NVB+NCB).
// BM=64, BN=128, BK=32, 2-buf LDS, reg prefetch-1 (R9/R14-proven schedule).
// A: fp16 image, 1 uint4/thread (row t>>2, oct t&3) — oproj's proven map.
// B: pre-tiled weights, 2 contiguous uint4/thread, linear LDS write.
// ---------------------------------------------------------------------------
__global__ __launch_bounds__(256) void k_front(const _Float16* __restrict__ val_h,
                                               const _Float16* __restrict__ qry_h,
                                               const _Float16* __restrict__ Wvt,
                                               const _Float16* __restrict__ Wsat,
                                               const float* __restrict__ refp,
                                               const float* __restrict__ bv,
                                               const float* __restrict__ bs,
                                               const float* __restrict__ ba,
                                               _Float16* __restrict__ vt,
                                               float* __restrict__ sx,
                                               float* __restrict__ sy,
                                               float* __restrict__ sw)
{
    __shared__ __align__(16) _Float16 Ah[2][4 * ASTR];   // 2 x 4288 B
    __shared__ __align__(16) _Float16 Bh[2][4096];       // 2 x 8192 B  [oct][nl][8]
    __shared__ float rp[64][8];                          // 2 KB (coords only)

    const int t = threadIdx.x;
    const int lane = t & 63, w = t >> 6;
    const int bid = blockIdx.x;
    const bool isv = (bid < NVB);

    int row0, n0;
    const _Float16* Asrc;
    const _Float16* Bt;
    if (isv) {
        n0 = (bid & 1) * 128;
        row0 = (bid >> 1) * 64;
        Asrc = val_h;
        Bt = Wvt + (size_t)(bid & 1) * GSTR;
    } else {
        const int cid = bid - NVB;
        const int g = cid % 3;
        n0 = g * 128;
        row0 = (cid / 3) * 64;
        Asrc = qry_h;
        Bt = Wsat + (size_t)g * GSTR;
        const int i0 = row0 * 8 + t;
        rp[t >> 3][t & 7] = refp[min(i0, MQ * 8 - 1)];
        const int i1 = i0 + 256;
        rp[32 + (t >> 3)][t & 7] = refp[min(i1, MQ * 8 - 1)];
    }

    // A staging map (oproj-proven): row arr, oct acl
    const int arr = t >> 2;   // 0..63
    const int acl = t & 3;

    const _Float16* gA0;
    {
        int r0i = row0 + arr;
        if (!isv) r0i = min(r0i, MQ - 1);
        gA0 = Asrc + (size_t)r0i * 256 + acl * 8;
    }

    uint4 ar0, br0, br1;
#define LOADT(kt) { ar0 = *reinterpret_cast<const uint4*>(gA0 + (kt) * 32); \
                    br0 = *reinterpret_cast<const uint4*>(Bt + (kt) * 4096 + t * 8);        \
                    br1 = *reinterpret_cast<const uint4*>(Bt + (kt) * 4096 + 2048 + t * 8); }

    LOADT(0);

    f32x4 acc[4][2];
#pragma unroll
    for (int fr = 0; fr < 4; ++fr)
#pragma unroll
        for (int fc = 0; fc < 2; ++fc) acc[fr][fc] = (f32x4){0.f, 0.f, 0.f, 0.f};

    const int rowb = lane & 15;
    const int kq = lane >> 4;
    int buf = 0;
#pragma unroll
    for (int kt = 0; kt < 8; ++kt) {
        *reinterpret_cast<uint4*>(&Ah[buf][acl * ASTR + arr * 8]) = ar0;
        *reinterpret_cast<uint4*>(&Bh[buf][t * 8])        = br0;
        *reinterpret_cast<uint4*>(&Bh[buf][2048 + t * 8]) = br1;
        if (kt < 7) LOADT(kt + 1);
        __syncthreads();

        half8 af[4], bf[2];
#pragma unroll
        for (int fr = 0; fr < 4; ++fr)
            af[fr] = *reinterpret_cast<const half8*>(&Ah[buf][kq * ASTR + (fr * 16 + rowb) * 8]);
#pragma unroll
        for (int fc = 0; fc < 2; ++fc)
            bf[fc] = *reinterpret_cast<const half8*>(&Bh[buf][kq * 1024 + (w * 32 + fc * 16 + rowb) * 8]);
#pragma unroll
        for (int fr = 0; fr < 4; ++fr)
#pragma unroll
            for (int fc = 0; fc < 2; ++fc)
                acc[fr][fc] = __builtin_amdgcn_mfma_f32_16x16x32_f16(af[fr], bf[fc], acc[fr][fc], 0, 0, 0);
        buf ^= 1;
    }
#undef LOADT

    // ---- epilogues (identical to R9/R14) ----
    if (isv) {
        const int b = (row0 >= NB_S) ? 1 : 0;
        const int sb = row0 - b * NB_S;
#pragma unroll
        for (int fc = 0; fc < 2; ++fc) {
            const int n = n0 + w * 32 + fc * 16 + rowb;
            const int h = n >> 5, hd = n & 31;
            const float bvn = bv[n];
#pragma unroll
            for (int fr = 0; fr < 4; ++fr) {
                const f32x4 c = acc[fr][fc];
#pragma unroll
                for (int j = 0; j < 4; ++j) {
                    const int m = fr * 16 + (lane >> 4) * 4 + j;
                    vt[((size_t)((b * NB_NH + h) * NB_S + (sb + m)) << 5) + hd] = (_Float16)(c[j] + bvn);
                }
            }
        }
    } else if (n0 < 256) {
#pragma unroll
        for (int fc = 0; fc < 2; ++fc) {
            const int n = n0 + w * 32 + fc * 16 + rowb;
            const int si = n >> 1, xy = n & 1;
            const int l = (n >> 3) & 3;
            const float dim = (float)(128 >> l);
            const float bsv = bs[n];
            float* dst = xy ? sy : sx;
#pragma unroll
            for (int fr = 0; fr < 4; ++fr) {
                const f32x4 c = acc[fr][fc];
#pragma unroll
                for (int j = 0; j < 4; ++j) {
                    const int m = fr * 16 + (lane >> 4) * 4 + j;
                    if (row0 + m < MQ) {
                        const float coord = rp[m][l * 2 + xy] * dim + (c[j] + bsv) - 0.5f;
                        dst[(size_t)(row0 + m) * 128 + si] = coord;
                    }
                }
            }
        }
    } else {
#pragma unroll
        for (int fc = 0; fc < 2; ++fc) {
            const int col = w * 32 + fc * 16 + rowb;
            const float bav = ba[col];
#pragma unroll
            for (int fr = 0; fr < 4; ++fr) {
                const f32x4 c = acc[fr][fc];
#pragma unroll
                for (int j = 0; j < 4; ++j) {
                    const int m = fr * 16 + (lane >> 4) * 4 + j;
                    float v = c[j] + bav;
                    float vm = v;
                    vm = fmaxf(vm, __shfl_xor(vm, 1));
                    vm = fmaxf(vm, __shfl_xor(vm, 2));
                    vm = fmaxf(vm, __shfl_xor(vm, 4));
                    vm = fmaxf(vm, __shfl_xor(vm, 8));
                    const float e = expf(v - vm);
                    float s = e;
                    s += __shfl_xor(s, 1);
                    s += __shfl_xor(s, 2);
                    s += __shfl_xor(s, 4);
                    s += __shfl_xor(s, 8);
                    if (row0 + m < MQ)
                        sw[(size_t)(row0 + m) * 128 + col] = e / s;
                }
            }
        }
    }
}

// ---------------------------------------------------------------------------
// gather: block = (16 queries, 1 head); head = blockIdx.x & 7 (XCD locality).
// ---------------------------------------------------------------------------
__global__ __launch_bounds__(256) void k_gather(const _Float16* __restrict__ vt,
                                                const float* __restrict__ sx,
                                                const float* __restrict__ sy,
                                                const float* __restrict__ sw,
                                                _Float16* __restrict__ tmp)
{
    __shared__ int   offs[16][16][4];
    __shared__ float wts[16][16][4];
    const int t = threadIdx.x;
    const int gid = blockIdx.x;
    const int h = gid & 7;
    const int row0 = (gid >> 3) * 16;
    const int b = (row0 >= NB_Q) ? 1 : 0;

    {
        const int r = t >> 4, s = t & 15;
        const size_t ci = (size_t)(row0 + r) * 128 + h * 16 + s;
        const float x = sx[ci], y = sy[ci], w = sw[ci];
        const int l = s >> 2;
        const int dim = 128 >> l;
        const int startL = (l == 0) ? 0 : (l == 1) ? 16384 : (l == 2) ? 20480 : 21504;
        const float x0f = floorf(x), y0f = floorf(y);
        const float lx = x - x0f, ly = y - y0f;
        const int ix = (int)x0f, iy = (int)y0f;
        const int ix0 = min(max(ix, 0), dim - 1), ix1 = min(max(ix + 1, 0), dim - 1);
        const int iy0 = min(max(iy, 0), dim - 1), iy1 = min(max(iy + 1, 0), dim - 1);
        const float vx0 = (ix >= 0 && ix < dim) ? 1.f : 0.f;
        const float vx1 = (ix + 1 >= 0 && ix + 1 < dim) ? 1.f : 0.f;
        const float vy0 = (iy >= 0 && iy < dim) ? 1.f : 0.f;
        const float vy1 = (iy + 1 >= 0 && iy + 1 < dim) ? 1.f : 0.f;
        offs[r][s][0] = (startL + iy0 * dim + ix0) * (NB_HD * 2);
        offs[r][s][1] = (startL + iy0 * dim + ix1) * (NB_HD * 2);
        offs[r][s][2] = (startL + iy1 * dim + ix0) * (NB_HD * 2);
        offs[r][s][3] = (startL + iy1 * dim + ix1) * (NB_HD * 2);
        wts[r][s][0] = w * (1.f - lx) * (1.f - ly) * vx0 * vy0;
        wts[r][s][1] = w * lx * (1.f - ly) * vx1 * vy0;
        wts[r][s][2] = w * (1.f - lx) * ly * vx0 * vy1;
        wts[r][s][3] = w * lx * ly * vx1 * vy1;
    }
    __syncthreads();

    const int r = t >> 4, hd2 = t & 15;
    const char* slab = reinterpret_cast<const char*>(vt)
                     + (size_t)(b * NB_NH + h) * NB_S * (NB_HD * 2);
    const int byo = hd2 * 4;
    float ax = 0.f, ay = 0.f;
#pragma unroll
    for (int s = 0; s < 16; ++s) {
        const int4   o = *reinterpret_cast<const int4*>(&offs[r][s][0]);
        const float4 w = *reinterpret_cast<const float4*>(&wts[r][s][0]);
        union { unsigned u; _Float16 h[2]; } c0, c1, c2, c3;
        c0.u = *reinterpret_cast<const unsigned*>(slab + (o.x + byo));
        c1.u = *reinterpret_cast<const unsigned*>(slab + (o.y + byo));
        c2.u = *reinterpret_cast<const unsigned*>(slab + (o.z + byo));
        c3.u = *reinterpret_cast<const unsigned*>(slab + (o.w + byo));
        ax = fmaf(w.x, (float)c0.h[0], ax); ay = fmaf(w.x, (float)c0.h[1], ay);
        ax = fmaf(w.y, (float)c1.h[0], ax); ay = fmaf(w.y, (float)c1.h[1], ay);
        ax = fmaf(w.z, (float)c2.h[0], ax); ay = fmaf(w.z, (float)c2.h[1], ay);
        ax = fmaf(w.w, (float)c3.h[0], ax); ay = fmaf(w.w, (float)c3.h[1], ay);
    }
    union { unsigned u; _Float16 h[2]; } p;
    p.h[0] = (_Float16)ax; p.h[1] = (_Float16)ay;
    *reinterpret_cast<unsigned*>(tmp + (size_t)(row0 + r) * 256 + h * 32 + hd2 * 2) = p.u;
}

// ---------------------------------------------------------------------------
// oproj: out = tmp @ Wo + bo. R14 champion verbatim.
// ---------------------------------------------------------------------------
__global__ __launch_bounds__(256) void k_oproj_mm(const _Float16* __restrict__ tmp,
                                                  const _Float16* __restrict__ Wot,
                                                  const float* __restrict__ bo,
                                                  float* __restrict__ out)
{
    __shared__ __align__(16) _Float16 Ao[2][4 * ASTR];
    __shared__ __align__(16) _Float16 Bh[2][4096];
    const int t = threadIdx.x;
    const int lane = t & 63, w = t >> 6;
    const int bid = blockIdx.x;
    const int n0 = (bid & 1) * 128;
    const int row0 = (bid >> 1) * 64;
    const _Float16* Bt = Wot + (size_t)(bid & 1) * GSTR;

    const int arr = t >> 2;   // A row 0..63
    const int acl = t & 3;    // A oct

    const _Float16* gA0 = tmp + (size_t)min(row0 + arr, MQ - 1) * 256 + acl * 8;

    uint4 ar0, br0, br1;
#define LOADT(kt) { ar0 = *reinterpret_cast<const uint4*>(gA0 + (kt) * 32); \
                    br0 = *reinterpret_cast<const uint4*>(Bt + (kt) * 4096 + t * 8);        \
                    br1 = *reinterpret_cast<const uint4*>(Bt + (kt) * 4096 + 2048 + t * 8); }

    LOADT(0);

    f32x4 acc[4][2];
#pragma unroll
    for (int fr = 0; fr < 4; ++fr)
#pragma unroll
        for (int fc = 0; fc < 2; ++fc) acc[fr][fc] = (f32x4){0.f, 0.f, 0.f, 0.f};

    const int rowb = lane & 15;
    const int kq = lane >> 4;
    int buf = 0;
#pragma unroll
    for (int kt = 0; kt < 8; ++kt) {
        *reinterpret_cast<uint4*>(&Ao[buf][acl * ASTR + arr * 8]) = ar0;
        *reinterpret_cast<uint4*>(&Bh[buf][t * 8])        = br0;
        *reinterpret_cast<uint4*>(&Bh[buf][2048 + t * 8]) = br1;
        if (kt < 7) LOADT(kt + 1);
        __syncthreads();

        half8 af[4], bf[2];
#pragma unroll
        for (int fr = 0; fr < 4; ++fr)
            af[fr] = *reinterpret_cast<const half8*>(&Ao[buf][kq * ASTR + (fr * 16 + rowb) * 8]);
#pragma unroll
        for (int fc = 0; fc < 2; ++fc)
            bf[fc] = *reinterpret_cast<const half8*>(&Bh[buf][kq * 1024 + (w * 32 + fc * 16 + rowb) * 8]);
#pragma unroll
        for (int fr = 0; fr < 4; ++fr)
#pragma unroll
            for (int fc = 0; fc < 2; ++fc)
                acc[fr][fc] = __builtin_amdgcn_mfma_f32_16x16x32_f16(af[fr], bf[fc], acc[fr][fc], 0, 0, 0);
        buf ^= 1;
    }
#undef LOADT

#pragma unroll
    for (int fc = 0; fc < 2; ++fc) {
        const int n = n0 + w * 32 + fc * 16 + rowb;
        const float bon = bo[n];
#pragma unroll
        for (int fr = 0; fr < 4; ++fr) {
            const f32x4 c = acc[fr][fc];
#pragma unroll
            for (int j = 0; j < 4; ++j) {
                const int m = fr * 16 + (lane >> 4) * 4 + j;
                if (row0 + m < MQ)
                    out[(size_t)(row0 + m) * 256 + n] = c[j] + bon;
            }
        }
    }
}

// ---------------------------------------------------------------------------
extern "C" void kernel_launch(void* const* d_in, const int* in_sizes, int n_in,
                              void* d_out, int out_size, void* d_ws, size_t ws_size,
                              hipStream_t stream)
{
    const float* query = (const float*)d_in[0];
    const float* refp  = (const float*)d_in[1];
    const float* value = (const float*)d_in[2];
    const float* Wv = (const float*)d_in[4];
    const float* bv = (const float*)d_in[5];
    const float* Ws = (const float*)d_in[6];
    const float* bs = (const float*)d_in[7];
    const float* Wa = (const float*)d_in[8];
    const float* ba = (const float*)d_in[9];
    const float* Wo = (const float*)d_in[10];
    const float* bo = (const float*)d_in[11];
    float* out = (float*)d_out;

    char* ws = (char*)d_ws;
    _Float16* vt_h  = (_Float16*)(ws + 0);          // 22,282,240 B
    _Float16* val_h = (_Float16*)(ws + 22282240);   // 22,282,240 B
    _Float16* qry_h = (_Float16*)(ws + 44564480);   // 10,240,000 B (aliases tmp)
    _Float16* tmp_h = qry_h;                        // gather writes after front
    _Float16* Wvt   = (_Float16*)(ws + 54804480);   //    131,072 B
    _Float16* Wsat  = (_Float16*)(ws + 54935552);   //    196,608 B
    _Float16* Wot   = (_Float16*)(ws + 55132160);   //    131,072 B
    float*    sxg   = (float*)   (ws + 55263232);   // 10,240,000 B
    float*    syg   = (float*)   (ws + 65503232);
    float*    swg   = (float*)   (ws + 75743232);   // ends 85,983,232

    hipLaunchKernelGGL(k_prepcvt, dim3(8836), dim3(256), 0, stream,
                       Wv, Ws, Wa, Wo, value, query, Wvt, Wsat, Wot, val_h, qry_h);
    hipLaunchKernelGGL(k_front, dim3(NVB + NCB), dim3(256), 0, stream,
                       val_h, qry_h, Wvt, Wsat, refp, bv, bs, ba,
                       vt_h, sxg, syg, swg);
    hipLaunchKernelGGL(k_gather, dim3(NB_B * NB_Q / 16 * NB_NH), dim3(256), 0, stream,
                       vt_h, sxg, syg, swg, tmp_h);
    hipLaunchKernelGGL(k_oproj_mm, dim3(MQB * 2), dim3(256), 0, stream,
                       tmp_h, Wot, bo, out);
}